// Round 10
// baseline (330.005 us; speedup 1.0000x reference)
//
#include <hip/hip_runtime.h>
#include <math.h>

typedef unsigned short u16;
typedef __bf16 bf16x8_t __attribute__((ext_vector_type(8)));
typedef float f32x4_t __attribute__((ext_vector_type(4)));
typedef float f32x16_t __attribute__((ext_vector_type(16)));

#define B_  2
#define S_  2048
#define D_  2048
#define H_  16
#define G_  4
#define DH_ 128

#define NEG_SENTINEL (-3.0e38f)
// 1/sqrt(128) * log2(e): folded into q at rope time so softmax uses exp2 directly
#define Q_SCALE (0.08838834764831843f * 1.4426950408889634f)

__device__ __forceinline__ float b2f(u16 u) {
    union { unsigned int i; float f; } v; v.i = ((unsigned int)u) << 16; return v.f;
}
__device__ __forceinline__ u16 f2b(float f) {
    union { float f; unsigned int i; } v; v.f = f;
    unsigned int r = v.i + 0x7fffu + ((v.i >> 16) & 1u);  // RNE
    return (u16)(r >> 16);
}

// XOR-swizzle (T2): permutes 16B chunks within a row's 8-chunk stripe.
// elem index ^= kxor(row); chunk index ^= swz8(row). Involution.
__device__ __forceinline__ int kxor(int r) {
    return (((r) & 7) ^ (((r) >> 3) & 1)) << 3;
}
__device__ __forceinline__ int swz8(int r) { return (r & 7) ^ ((r >> 3) & 1); }

// async global->LDS, 16B per lane (dest = wave-uniform base + lane*16)
__device__ __forceinline__ void gld16(const u16* g, u16* l) {
    __builtin_amdgcn_global_load_lds(
        (const __attribute__((address_space(1))) unsigned int*)g,
        (__attribute__((address_space(3))) unsigned int*)l, 16, 0, 0);
}

// v_cvt_pk_bf16_f32: pack two f32 -> two bf16 in one u32 (lo in low half)
__device__ __forceinline__ unsigned int cvtpk_bf16(float lo, float hi) {
    unsigned int w;
    asm("v_cvt_pk_bf16_f32 %0, %1, %2" : "=v"(w) : "v"(lo), "v"(hi));
    return w;
}

// ---------------------------------------------------------------------------
// Phase-1 fused kernel: trig table + x cast + Wq/Wk/Wv transposes.
// grid = 512 + 4096 + 4096 + 1024 + 1024 = 10752 blocks, decode on blockIdx.
// Transpose WRITES vectorized (G13): 2 rows packed per uint = 4B/lane
// coalesced (was 2B/lane scalar u16).
// ---------------------------------------------------------------------------
__global__ __launch_bounds__(256) void prep1(
    const float* __restrict__ x,  const float* __restrict__ Wq,
    const float* __restrict__ Wk, const float* __restrict__ Wv,
    u16* __restrict__ xb, u16* __restrict__ WqT, u16* __restrict__ WkvT,
    float* __restrict__ tab) {
    __shared__ u16 t[32][33];
    const int id = blockIdx.x, tid = threadIdx.x;

    if (id < 512) {                       // build_trig
        int idx = id * 256 + tid;         // 131072 = 2048*64
        int d = idx & 63, s = idx >> 6;
        float inv = exp2f(-(float)d * (13.287712379549449f / 64.f));
        float sn, cs;
        sincosf((float)s * inv, &sn, &cs);
        tab[idx * 2]     = cs;
        tab[idx * 2 + 1] = sn;
        return;
    }
    if (id < 4608) {                      // cast_x
        int i = ((id - 512) * 256 + tid) * 8;
        float4 a = *(const float4*)(x + i);
        float4 b = *(const float4*)(x + i + 4);
        u16 o[8] = {f2b(a.x), f2b(a.y), f2b(a.z), f2b(a.w),
                    f2b(b.x), f2b(b.y), f2b(b.z), f2b(b.w)};
        *(uint4*)(xb + i) = *(uint4*)o;
        return;
    }
    // W transposes: f32 [2048][C] -> bf16 [C][2048]
    const float* in; u16* out; int bx, by, C;
    if (id < 8704)      { int k = id - 4608; bx = k & 63; by = k >> 6; in = Wq; out = WqT;               C = 2048; }
    else if (id < 9728) { int k = id - 8704; bx = k & 15; by = k >> 4; in = Wk; out = WkvT;              C = 512;  }
    else                { int k = id - 9728; bx = k & 15; by = k >> 4; in = Wv; out = WkvT + (size_t)512 * 2048; C = 512; }
    const int c0 = bx * 32, r0 = by * 32;
    const int j = tid & 31, i = tid >> 5;
#pragma unroll
    for (int p = 0; p < 4; ++p)
        t[i + 8 * p][j] = f2b(in[(size_t)(r0 + i + 8 * p) * C + c0 + j]);
    __syncthreads();
    // write: lane pair-of-rows -> one uint; 16 lanes cover 64B contiguous
    const int j2 = tid & 15, i2 = tid >> 4;
#pragma unroll
    for (int p = 0; p < 2; ++p) {
        int col = i2 + 16 * p;            // 0..31
        unsigned int w = (unsigned int)t[2 * j2][col] |
                         ((unsigned int)t[2 * j2 + 1][col] << 16);
        *(unsigned int*)(&out[(size_t)(c0 + col) * 2048 + r0 + 2 * j2]) = w;
    }
}

// ---------------------------------------------------------------------------
// Fused projection GEMM: [q | kv] = xb @ [WqT | WkvT]^T in ONE launch.
// M=4096, N=3072, K=2048, tile 128x128, grid (24,32) = 768 blocks = 3/CU.
// T1 XCD-chunked swizzle: linear id (by*24+bx); XCD = lin%8 (round-robin
// dispatch assumption, m157/m192); each XCD owns a 4-Mrow x 24-Ncol slab
// (96 blocks = its exact residency) -> per K-iter the XCD touches only
// 4 A-subtiles + 24 B-subtiles = 448KB (L2-resident, lockstep sweep) ->
// fewer L2 fills than round-robin scatter. 768 = 8*96 exactly (bijective).
// ---------------------------------------------------------------------------
__global__ __launch_bounds__(256) void gemm_proj(
    const u16* __restrict__ A, const u16* __restrict__ BT,
    u16* __restrict__ qraw, u16* __restrict__ kvraw) {
    const int K = 2048;
    __shared__ __align__(16) u16 As[128 * 64];
    __shared__ __align__(16) u16 Bs[128 * 64];
    const int tid  = threadIdx.x;
    const int lane = tid & 63;
    const int wave = tid >> 6;
    const int wm = wave >> 1, wn = wave & 1;
    const int quad = lane >> 4, l16 = lane & 15;
    const int lr = lane >> 3, lc = lane & 7;

    // T1 swizzle (see header)
    const int lin = blockIdx.y * 24 + blockIdx.x;
    const int xcd = lin & 7, jj = lin >> 3;
    const int m0 = (xcd * 4 + jj / 24) * 128;
    const int n0 = (jj % 24) * 128;

    f32x4_t acc[4][4] = {};

    for (int k0 = 0; k0 < K; k0 += 64) {
#pragma unroll
        for (int i = 0; i < 4; ++i) {
            int rb = wave * 32 + i * 8;
            int r  = rb + lr;
            int sc = (lc ^ swz8(r)) << 3;
            gld16(A  + (size_t)(m0 + r) * K + k0 + sc, &As[rb * 64]);
            gld16(BT + (size_t)(n0 + r) * K + k0 + sc, &Bs[rb * 64]);
        }
        __syncthreads();
#pragma unroll
        for (int ks = 0; ks < 2; ++ks) {
            const int kch = ks * 4 + quad;
            bf16x8_t a[4], b[4];
#pragma unroll
            for (int mt = 0; mt < 4; ++mt) {
                int row = wm * 64 + mt * 16 + l16;
                a[mt] = *(const bf16x8_t*)(&As[row * 64 + ((kch ^ swz8(row)) << 3)]);
            }
#pragma unroll
            for (int nt = 0; nt < 4; ++nt) {
                int row = wn * 64 + nt * 16 + l16;
                b[nt] = *(const bf16x8_t*)(&Bs[row * 64 + ((kch ^ swz8(row)) << 3)]);
            }
#pragma unroll
            for (int mt = 0; mt < 4; ++mt)
#pragma unroll
                for (int nt = 0; nt < 4; ++nt)
                    acc[mt][nt] = __builtin_amdgcn_mfma_f32_16x16x32_bf16(
                        a[mt], b[nt], acc[mt][nt], 0, 0, 0);
        }
        __syncthreads();
    }
#pragma unroll
    for (int mt = 0; mt < 4; ++mt)
#pragma unroll
        for (int nt = 0; nt < 4; ++nt)
#pragma unroll
            for (int r = 0; r < 4; ++r) {
                int m = m0 + wm * 64 + mt * 16 + quad * 4 + r;
                int n = n0 + wn * 64 + nt * 16 + l16;
                u16 v = f2b(acc[mt][nt][r]);
                if (n < 2048) qraw[(size_t)m * 2048 + n] = v;
                else          kvraw[(size_t)m * 1024 + (n - 2048)] = v;
            }
}

// ---------------------------------------------------------------------------
// NT GEMM (out-projection): C[M][N] = A[M][K] * BT[N][K]^T, f32 out.
// Unchanged (control).
// ---------------------------------------------------------------------------
__global__ __launch_bounds__(256) void gemm_nt(
    const u16* __restrict__ A, const u16* __restrict__ BT, float* __restrict__ C,
    int M, int N, int K) {
    __shared__ __align__(16) u16 As[128 * 64];
    __shared__ __align__(16) u16 Bs[128 * 64];
    const int tid  = threadIdx.x;
    const int lane = tid & 63;
    const int wave = tid >> 6;
    const int wm = wave >> 1, wn = wave & 1;
    const int quad = lane >> 4, l16 = lane & 15;
    const int lr = lane >> 3, lc = lane & 7;
    const int m0 = blockIdx.y * 128, n0 = blockIdx.x * 128;

    f32x4_t acc[4][4] = {};

    for (int k0 = 0; k0 < K; k0 += 64) {
#pragma unroll
        for (int i = 0; i < 4; ++i) {
            int rb = wave * 32 + i * 8;
            int r  = rb + lr;
            int sc = (lc ^ swz8(r)) << 3;
            gld16(A  + (size_t)(m0 + r) * K + k0 + sc, &As[rb * 64]);
            gld16(BT + (size_t)(n0 + r) * K + k0 + sc, &Bs[rb * 64]);
        }
        __syncthreads();
#pragma unroll
        for (int ks = 0; ks < 2; ++ks) {
            const int kch = ks * 4 + quad;
            bf16x8_t a[4], b[4];
#pragma unroll
            for (int mt = 0; mt < 4; ++mt) {
                int row = wm * 64 + mt * 16 + l16;
                a[mt] = *(const bf16x8_t*)(&As[row * 64 + ((kch ^ swz8(row)) << 3)]);
            }
#pragma unroll
            for (int nt = 0; nt < 4; ++nt) {
                int row = wn * 64 + nt * 16 + l16;
                b[nt] = *(const bf16x8_t*)(&Bs[row * 64 + ((kch ^ swz8(row)) << 3)]);
            }
#pragma unroll
            for (int mt = 0; mt < 4; ++mt)
#pragma unroll
                for (int nt = 0; nt < 4; ++nt)
                    acc[mt][nt] = __builtin_amdgcn_mfma_f32_16x16x32_bf16(
                        a[mt], b[nt], acc[mt][nt], 0, 0, 0);
        }
        __syncthreads();
    }
#pragma unroll
    for (int mt = 0; mt < 4; ++mt)
#pragma unroll
        for (int nt = 0; nt < 4; ++nt)
#pragma unroll
            for (int r = 0; r < 4; ++r) {
                int m = m0 + wm * 64 + mt * 16 + quad * 4 + r;
                int n = n0 + wn * 64 + nt * 16 + l16;
                C[(size_t)m * N + n] = acc[mt][nt][r];
            }
}

// ---------------------------------------------------------------------------
// Phase-3 fused kernel: rope_q + k_prep + v_prep + Wo transpose.
// Vectorized (G13): rope_q/k_prep handle 2 consecutive d per thread (4B uint
// loads/stores, float4 trig loads); vt/WoT transpose writes pack 2 rows/uint.
// grid = 8192 + 2048 + 2048 + 4096 = 16384 blocks.
// ---------------------------------------------------------------------------
__global__ __launch_bounds__(256) void prep3(
    u16* __restrict__ qraw, const u16* __restrict__ kvraw,
    float* __restrict__ kc, u16* __restrict__ kb,
    float* __restrict__ vc, u16* __restrict__ vt,
    const float* __restrict__ Wo, u16* __restrict__ WoT,
    const float* __restrict__ tab) {
    __shared__ u16 tls[32][33];
    const int id = blockIdx.x, tid = threadIdx.x;

    if (id < 8192) {                      // rope_q: 2 d's per thread
        int idx = id * 256 + tid;         // 2,097,152 total
        int d = (idx & 31) * 2;
        int t = idx >> 5;
        int h = t & 15; t >>= 4;
        int s = t & 2047;
        int b = t >> 11;
        size_t base = ((size_t)(b * S_ + s) * H_ + h) * DH_;
        unsigned int lo = *(const unsigned int*)(qraw + base + d);
        unsigned int hi = *(const unsigned int*)(qraw + base + d + 64);
        float4 cs = *(const float4*)(tab + ((size_t)((s << 6) | d)) * 2);
        float x1a = b2f((u16)lo), x1b = b2f((u16)(lo >> 16));
        float x2a = b2f((u16)hi), x2b = b2f((u16)(hi >> 16));
        float r1a = (x1a * cs.x - x2a * cs.y) * Q_SCALE;
        float r1b = (x1b * cs.z - x2b * cs.w) * Q_SCALE;
        float r2a = (x2a * cs.x + x1a * cs.y) * Q_SCALE;
        float r2b = (x2b * cs.z + x1b * cs.w) * Q_SCALE;
        *(unsigned int*)(qraw + base + d)      = (unsigned int)f2b(r1a) | ((unsigned int)f2b(r1b) << 16);
        *(unsigned int*)(qraw + base + d + 64) = (unsigned int)f2b(r2a) | ((unsigned int)f2b(r2b) << 16);
        return;
    }
    if (id < 10240) {                     // k_prep: 2 d's per thread
        int idx = (id - 8192) * 256 + tid;  // 524,288 total
        int d = (idx & 31) * 2;
        int t = idx >> 5;
        int g = t & 3; t >>= 2;
        int s = t & 2047;
        int b = t >> 11;
        const u16* src = kvraw + (size_t)(b * S_ + s) * 1024 + g * DH_;
        unsigned int lo = *(const unsigned int*)(src + d);
        unsigned int hi = *(const unsigned int*)(src + d + 64);
        float4 cs = *(const float4*)(tab + ((size_t)((s << 6) | d)) * 2);
        float x1a = b2f((u16)lo), x1b = b2f((u16)(lo >> 16));
        float x2a = b2f((u16)hi), x2b = b2f((u16)(hi >> 16));
        float r1a = x1a * cs.x - x2a * cs.y;
        float r1b = x1b * cs.z - x2b * cs.w;
        float r2a = x2a * cs.x + x1a * cs.y;
        float r2b = x2b * cs.z + x1b * cs.w;
        size_t o = ((size_t)(b * G_ + g) * S_ + s) * DH_;
        *(float2*)(kc + o + d)      = make_float2(r1a, r1b);
        *(float2*)(kc + o + d + 64) = make_float2(r2a, r2b);
        *(unsigned int*)(kb + o + d)      = (unsigned int)f2b(r1a) | ((unsigned int)f2b(r1b) << 16);
        *(unsigned int*)(kb + o + d + 64) = (unsigned int)f2b(r2a) | ((unsigned int)f2b(r2b) << 16);
        return;
    }
    if (id < 12288) {                     // v_prep
        int k = id - 10240;
        const int s0 = (k & 63) * 32, d0 = ((k >> 6) & 3) * 32;
        const int bg = k >> 8, b = bg >> 2, g = bg & 3;
        const int j = tid & 31, i = tid >> 5;
#pragma unroll
        for (int p = 0; p < 4; ++p) {
            int s = s0 + i + 8 * p;
            u16 v = kvraw[(size_t)(b * S_ + s) * 1024 + 512 + g * DH_ + d0 + j];
            tls[i + 8 * p][j] = v;
            vc[((size_t)bg * S_ + s) * DH_ + d0 + j] = b2f(v);
        }
        __syncthreads();
        // vt write: pack 2 s's per uint (tls rows = s-local, cols = d-local)
        const int j2 = tid & 15, i2 = tid >> 4;
#pragma unroll
        for (int p = 0; p < 2; ++p) {
            int col = i2 + 16 * p;        // d-local 0..31
            unsigned int w = (unsigned int)tls[2 * j2][col] |
                             ((unsigned int)tls[2 * j2 + 1][col] << 16);
            *(unsigned int*)(&vt[((size_t)bg * DH_ + d0 + col) * S_ + s0 + 2 * j2]) = w;
        }
        return;
    }
    {                                     // Wo transpose
        int k = id - 12288;
        const int c0 = (k & 63) * 32, r0 = (k >> 6) * 32;
        const int j = tid & 31, i = tid >> 5;
#pragma unroll
        for (int p = 0; p < 4; ++p)
            tls[i + 8 * p][j] = f2b(Wo[(size_t)(r0 + i + 8 * p) * 2048 + c0 + j]);
        __syncthreads();
        const int j2 = tid & 15, i2 = tid >> 4;
#pragma unroll
        for (int p = 0; p < 2; ++p) {
            int col = i2 + 16 * p;
            unsigned int w = (unsigned int)tls[2 * j2][col] |
                             ((unsigned int)tls[2 * j2 + 1][col] << 16);
            *(unsigned int*)(&WoT[(size_t)(c0 + col) * 2048 + r0 + 2 * j2]) = w;
        }
    }
}

// ---------------------------------------------------------------------------
// Flash attention v10 (unchanged, control): 32x32 swapped QK^T, static-max
// softmax, split pairs, 32 KiB LDS, gld16 staging, 2 blocks/CU.
// ---------------------------------------------------------------------------
__global__ __launch_bounds__(256, 2) void flash_attn(
    const u16* __restrict__ q, const u16* __restrict__ kb,
    const u16* __restrict__ vt, u16* __restrict__ ctx) {
    __shared__ __align__(16) u16 Ks[64 * 128];   // [kv 64][d 128], swizzled
    __shared__ __align__(16) u16 Vs[128 * 64];   // [d 128][kv 64], swizzled

    const int tid  = threadIdx.x;
    const int lane = tid & 63;
    const int wave = tid >> 6;
    const int hi = lane >> 5, l31 = lane & 31;

    const int id = blockIdx.x;
    const int tslot = id & 7;
    const int h = (id >> 3) & 15;
    const int b = (id >> 7) & 1;
    const int tile = (id >> 8) ? (15 - tslot) : tslot;
    const int g = h >> 2;  // H/G = 4

    const u16* Kp  = kb + (size_t)(b * G_ + g) * S_ * DH_;
    const u16* Vtp = vt + (size_t)(b * G_ + g) * DH_ * S_;

    int krow[4], ksc[4], vrow[4], vsc[4];
#pragma unroll
    for (int i = 0; i < 4; ++i) {
        int c = tid + 256 * i;
        krow[i] = c >> 4; ksc[i] = (((c & 15) ^ swz8(c >> 4)) << 3);
        vrow[i] = c >> 3; vsc[i] = (((c & 7) ^ swz8(c >> 3)) << 3);
    }

    const int t0 = tile * 128;
    const int q0w = t0 + wave * 32;
    const int niter = 2 * tile + 2;

    auto stageK = [&](int t) {
        const u16* src = Kp + (size_t)t * 64 * DH_;
#pragma unroll
        for (int i = 0; i < 4; ++i)
            gld16(src + (size_t)krow[i] * DH_ + ksc[i], &Ks[wave * 512 + i * 2048]);
    };
    auto stageV = [&](int t) {
        const u16* src = Vtp + t * 64;
#pragma unroll
        for (int i = 0; i < 4; ++i)
            gld16(src + (size_t)vrow[i] * S_ + vsc[i], &Vs[wave * 512 + i * 2048]);
    };

    bf16x8_t qf[8];
#pragma unroll
    for (int dk = 0; dk < 8; ++dk)
        qf[dk] = *(const bf16x8_t*)(
            q + ((size_t)(b * S_ + q0w + l31) * H_ + h) * DH_ + dk * 16 + hi * 8);

    f32x16_t o[4] = {};   // O[q=crow(r,hi)][d = nb*32 + l31]
    float l_i = 0.f;

    stageK(0);
    stageV(0);
    __syncthreads();

    for (int it = 0; it < niter; ++it) {
        const int kv0 = it * 64;
        const bool comp = (q0w + 31 >= kv0);  // wave-uniform

        f32x16_t s[2] = {};
        if (comp) {
#pragma unroll
            for (int dk = 0; dk < 8; ++dk) {
                const int col = dk * 16 + hi * 8;
                bf16x8_t kf0 = *(const bf16x8_t*)(
                    &Ks[l31 * 128 + (col ^ kxor(l31))]);
                bf16x8_t kf1 = *(const bf16x8_t*)(
                    &Ks[(32 + l31) * 128 + (col ^ kxor(32 + l31))]);
                s[0] = __builtin_amdgcn_mfma_f32_32x32x16_bf16(kf0, qf[dk], s[0], 0, 0, 0);
                s[1] = __builtin_amdgcn_mfma_f32_32x32x16_bf16(kf1, qf[dk], s[1], 0, 0, 0);
            }
        }
        __syncthreads();                 // V(it) visible; all waves done with Ks
        if (it + 1 < niter) stageK(it + 1);

        if (comp) {
            if (kv0 + 63 > q0w) {
                const int qg = q0w + l31;
#pragma unroll
                for (int t = 0; t < 2; ++t)
#pragma unroll
                    for (int r = 0; r < 16; ++r) {
                        int kvr = kv0 + t * 32 + (r & 3) + 8 * (r >> 2) + 4 * hi;
                        if (kvr > qg) s[t][r] = NEG_SENTINEL;
                    }
            }
            // static-max softmax: P = exp2(s) directly
            float sum[16];
#pragma unroll
            for (int i = 0; i < 16; ++i) {
                float p0 = exp2f(s[0][i]);
                float p1 = exp2f(s[1][i]);
                s[0][i] = p0; s[1][i] = p1;
                sum[i] = p0 + p1;
            }
#pragma unroll
            for (int w = 8; w >= 1; w >>= 1)
#pragma unroll
                for (int i = 0; i < w; ++i) sum[i] += sum[i + w];
            l_i += sum[0] + __shfl_xor(sum[0], 32);

            bf16x8_t pa[4];
#pragma unroll
            for (int ks = 0; ks < 4; ++ks) {
                const int t = ks >> 1, u8 = (ks & 1) * 8;
                unsigned int a0 = cvtpk_bf16(s[t][u8 + 0], s[t][u8 + 1]);
                unsigned int a1 = cvtpk_bf16(s[t][u8 + 2], s[t][u8 + 3]);
                unsigned int b0 = cvtpk_bf16(s[t][u8 + 4], s[t][u8 + 5]);
                unsigned int b1 = cvtpk_bf16(s[t][u8 + 6], s[t][u8 + 7]);
                asm("v_permlane32_swap_b32 %0, %1" : "+v"(a0), "+v"(b0));
                asm("v_permlane32_swap_b32 %0, %1" : "+v"(a1), "+v"(b1));
                union { unsigned int w[4]; bf16x8_t v; } pk;
                pk.w[0] = a0; pk.w[1] = a1; pk.w[2] = b0; pk.w[3] = b1;
                pa[ks] = pk.v;
            }
#pragma unroll
            for (int ks = 0; ks < 4; ++ks) {
                const int col = ks * 16 + hi * 8;
#pragma unroll
                for (int nb = 0; nb < 4; ++nb) {
                    const int row = nb * 32 + l31;
                    bf16x8_t vb = *(const bf16x8_t*)(
                        &Vs[row * 64 + (col ^ kxor(row))]);
                    o[nb] = __builtin_amdgcn_mfma_f32_32x32x16_bf16(
                        pa[ks], vb, o[nb], 0, 0, 0);
                }
            }
        }
        __syncthreads();                 // K(it+1) visible; all waves done with Vs
        if (it + 1 < niter) stageV(it + 1);
    }
    float il = 1.f / l_i;
#pragma unroll
    for (int r = 0; r < 16; ++r) {
        const int crow = (r & 3) + 8 * (r >> 2) + 4 * hi;
        float ilr = __shfl(il, crow);
        const int s_idx = q0w + crow;
#pragma unroll
        for (int nb = 0; nb < 4; ++nb)
            ctx[((size_t)(b * S_ + s_idx) * H_ + h) * DH_ + nb * 32 + l31] =
                f2b(o[nb][r] * ilr);
    }
}

// ---------------------------------------------------------------------------
extern "C" void kernel_launch(void* const* d_in, const int* in_sizes, int n_in,
                              void* d_out, int out_size, void* d_ws, size_t ws_size,
                              hipStream_t stream) {
    const float* x  = (const float*)d_in[0];
    const float* Wq = (const float*)d_in[1];
    const float* Wk = (const float*)d_in[2];
    const float* Wv = (const float*)d_in[3];
    const float* Wo = (const float*)d_in[4];
    // d_in[5] = mask (unused; causal computed analytically)

    float* out    = (float*)d_out;                           // [B][S][H*DH]  8,388,608 f32
    float* kc_out = out + (size_t)B_ * S_ * H_ * DH_;        // [B][G][S][DH] 2,097,152 f32
    float* vc_out = kc_out + (size_t)B_ * G_ * S_ * DH_;     // [B][G][S][DH] 2,097,152 f32

    // Borrow `out` f32 region (= 16M u16) as early scratch; both buffers are
    // dead before the final gemm writes `out` (single stream, serialized).
    u16* outw = (u16*)d_out;
    u16* xb   = outw;             // 8M u16, live phases 1-2 (x cast to bf16)
    u16* qraw = outw + 8388608;   // 8M u16, live phases 2-4

    // Workspace overlays (u16 offsets; phases single-stream serialized):
    u16* ws    = (u16*)d_ws;
    u16* WqT   = ws;              // 4M u16, phases 1-2  [bytes 0..8M)
    u16* WoT   = ws;              // 4M u16, phases 3-5  (same slot, after proj)
    u16* WkvT  = ws + 4194304;    // 2M u16, phases 1-2  [8M..12M) -- contiguous
                                  //   with WqT => fused BT[3072][2048]
    u16* kb    = ws + 4194304;    // 2M u16, phases 3-4
    u16* vt    = ws + 6291456;    // 2M u16, phases 3-4  [12M..16.8M)
    u16* kvraw = ws + 8388608;    // 4M u16, phases 2-3  [16.8M..25.2M)
    u16* ctx   = ws + 8388608;    // 8M u16, phases 4-5
    float* tab = (float*)(ws + 12582912);  // 1 MB trig table, phases 1-3
                                           // (inside ctx region, dead by ph 4)

    dim3 blk(256);
    // phase 1: trig + cast + Wq/Wk/Wv transposes (one launch)
    prep1<<<dim3(10752), blk, 0, stream>>>(x, Wq, Wk, Wv, xb, WqT, WkvT, tab);

    // phase 2: fused q+kv projection (768 blocks = 3/CU, T1 XCD swizzle)
    gemm_proj<<<dim3(24, 32), blk, 0, stream>>>(xb, WqT, qraw, kvraw);

    // phase 3: rope_q + k_prep + v_prep + Wo transpose (one launch, vectorized)
    prep3<<<dim3(16384), blk, 0, stream>>>(qraw, kvraw, kc_out, kb, vc_out, vt,
                                           Wo, WoT, tab);

    // phase 4: attention (static-max softmax, split pairs, 2 blocks/CU)
    flash_attn<<<dim3(512), blk, 0, stream>>>(qraw, kb, vt, ctx);

    // phase 5: output projection (f32 out)
    gemm_nt<<<dim3(16, 32), blk, 0, stream>>>(ctx, WoT, out, 4096, 2048, 2048);
}

// Round 12
// 329.228 us; speedup vs baseline: 1.0024x; 1.0024x over previous
//
#include <hip/hip_runtime.h>
#include <math.h>

typedef unsigned short u16;
typedef __bf16 bf16x8_t __attribute__((ext_vector_type(8)));
typedef float f32x4_t __attribute__((ext_vector_type(4)));
typedef float f32x16_t __attribute__((ext_vector_type(16)));

#define B_  2
#define S_  2048
#define D_  2048
#define H_  16
#define G_  4
#define DH_ 128

#define NEG_SENTINEL (-3.0e38f)
// 1/sqrt(128) * log2(e): folded into q at rope time so softmax uses exp2 directly
#define Q_SCALE (0.08838834764831843f * 1.4426950408889634f)

__device__ __forceinline__ float b2f(u16 u) {
    union { unsigned int i; float f; } v; v.i = ((unsigned int)u) << 16; return v.f;
}
__device__ __forceinline__ u16 f2b(float f) {
    union { float f; unsigned int i; } v; v.f = f;
    unsigned int r = v.i + 0x7fffu + ((v.i >> 16) & 1u);  // RNE
    return (u16)(r >> 16);
}

// XOR-swizzle (T2): permutes 16B chunks within a row's 8-chunk stripe.
// elem index ^= kxor(row); chunk index ^= swz8(row). Involution.
__device__ __forceinline__ int kxor(int r) {
    return (((r) & 7) ^ (((r) >> 3) & 1)) << 3;
}
__device__ __forceinline__ int swz8(int r) { return (r & 7) ^ ((r >> 3) & 1); }

// async global->LDS, 16B per lane (dest = wave-uniform base + lane*16)
__device__ __forceinline__ void gld16(const u16* g, u16* l) {
    __builtin_amdgcn_global_load_lds(
        (const __attribute__((address_space(1))) unsigned int*)g,
        (__attribute__((address_space(3))) unsigned int*)l, 16, 0, 0);
}

// v_cvt_pk_bf16_f32: pack two f32 -> two bf16 in one u32 (lo in low half)
__device__ __forceinline__ unsigned int cvtpk_bf16(float lo, float hi) {
    unsigned int w;
    asm("v_cvt_pk_bf16_f32 %0, %1, %2" : "=v"(w) : "v"(lo), "v"(hi));
    return w;
}

// ---------------------------------------------------------------------------
// Phase-1 fused kernel: trig table + x cast + Wq/Wk/Wv transposes.
// grid = 512 + 4096 + 4096 + 1024 + 1024 = 10752 blocks, decode on blockIdx.
// Transpose WRITES vectorized (G13): 2 rows packed per uint = 4B/lane.
// ---------------------------------------------------------------------------
__global__ __launch_bounds__(256) void prep1(
    const float* __restrict__ x,  const float* __restrict__ Wq,
    const float* __restrict__ Wk, const float* __restrict__ Wv,
    u16* __restrict__ xb, u16* __restrict__ WqT, u16* __restrict__ WkvT,
    float* __restrict__ tab) {
    __shared__ u16 t[32][33];
    const int id = blockIdx.x, tid = threadIdx.x;

    if (id < 512) {                       // build_trig
        int idx = id * 256 + tid;         // 131072 = 2048*64
        int d = idx & 63, s = idx >> 6;
        float inv = exp2f(-(float)d * (13.287712379549449f / 64.f));
        float sn, cs;
        sincosf((float)s * inv, &sn, &cs);
        tab[idx * 2]     = cs;
        tab[idx * 2 + 1] = sn;
        return;
    }
    if (id < 4608) {                      // cast_x
        int i = ((id - 512) * 256 + tid) * 8;
        float4 a = *(const float4*)(x + i);
        float4 b = *(const float4*)(x + i + 4);
        u16 o[8] = {f2b(a.x), f2b(a.y), f2b(a.z), f2b(a.w),
                    f2b(b.x), f2b(b.y), f2b(b.z), f2b(b.w)};
        *(uint4*)(xb + i) = *(uint4*)o;
        return;
    }
    // W transposes: f32 [2048][C] -> bf16 [C][2048]
    const float* in; u16* out; int bx, by, C;
    if (id < 8704)      { int k = id - 4608; bx = k & 63; by = k >> 6; in = Wq; out = WqT;               C = 2048; }
    else if (id < 9728) { int k = id - 8704; bx = k & 15; by = k >> 4; in = Wk; out = WkvT;              C = 512;  }
    else                { int k = id - 9728; bx = k & 15; by = k >> 4; in = Wv; out = WkvT + (size_t)512 * 2048; C = 512; }
    const int c0 = bx * 32, r0 = by * 32;
    const int j = tid & 31, i = tid >> 5;
#pragma unroll
    for (int p = 0; p < 4; ++p)
        t[i + 8 * p][j] = f2b(in[(size_t)(r0 + i + 8 * p) * C + c0 + j]);
    __syncthreads();
    const int j2 = tid & 15, i2 = tid >> 4;
#pragma unroll
    for (int p = 0; p < 2; ++p) {
        int col = i2 + 16 * p;            // 0..31
        unsigned int w = (unsigned int)t[2 * j2][col] |
                         ((unsigned int)t[2 * j2 + 1][col] << 16);
        *(unsigned int*)(&out[(size_t)(c0 + col) * 2048 + r0 + 2 * j2]) = w;
    }
}

// ---------------------------------------------------------------------------
// Fused projection GEMM: [q | kv] = xb @ [WqT | WkvT]^T in ONE launch.
// M=4096, N=3072, K=2048, tile 128x128, grid (24,32) = 768 blocks = 3/CU.
// R9-proven structure (gld16 + swz8 source swizzle, single buffer; issue ->
// __syncthreads (drains vmcnt) -> consume). R10's T1 swizzle reverted
// (FETCH 80->108 MB); R11's phase-split reverted (correctness failure --
// see journal: suspected alias-informed vmcnt drain at barrier; re-attempt
// only with explicit asm vmcnt drain + race screening).
// ---------------------------------------------------------------------------
__global__ __launch_bounds__(256) void gemm_proj(
    const u16* __restrict__ A, const u16* __restrict__ BT,
    u16* __restrict__ qraw, u16* __restrict__ kvraw) {
    const int K = 2048;
    __shared__ __align__(16) u16 As[128 * 64];
    __shared__ __align__(16) u16 Bs[128 * 64];
    const int tid  = threadIdx.x;
    const int lane = tid & 63;
    const int wave = tid >> 6;
    const int wm = wave >> 1, wn = wave & 1;
    const int quad = lane >> 4, l16 = lane & 15;
    const int lr = lane >> 3, lc = lane & 7;
    const int m0 = blockIdx.y * 128, n0 = blockIdx.x * 128;

    f32x4_t acc[4][4] = {};

    for (int k0 = 0; k0 < K; k0 += 64) {
#pragma unroll
        for (int i = 0; i < 4; ++i) {
            int rb = wave * 32 + i * 8;
            int r  = rb + lr;
            int sc = (lc ^ swz8(r)) << 3;
            gld16(A  + (size_t)(m0 + r) * K + k0 + sc, &As[rb * 64]);
            gld16(BT + (size_t)(n0 + r) * K + k0 + sc, &Bs[rb * 64]);
        }
        __syncthreads();
#pragma unroll
        for (int ks = 0; ks < 2; ++ks) {
            const int kch = ks * 4 + quad;
            bf16x8_t a[4], b[4];
#pragma unroll
            for (int mt = 0; mt < 4; ++mt) {
                int row = wm * 64 + mt * 16 + l16;
                a[mt] = *(const bf16x8_t*)(&As[row * 64 + ((kch ^ swz8(row)) << 3)]);
            }
#pragma unroll
            for (int nt = 0; nt < 4; ++nt) {
                int row = wn * 64 + nt * 16 + l16;
                b[nt] = *(const bf16x8_t*)(&Bs[row * 64 + ((kch ^ swz8(row)) << 3)]);
            }
#pragma unroll
            for (int mt = 0; mt < 4; ++mt)
#pragma unroll
                for (int nt = 0; nt < 4; ++nt)
                    acc[mt][nt] = __builtin_amdgcn_mfma_f32_16x16x32_bf16(
                        a[mt], b[nt], acc[mt][nt], 0, 0, 0);
        }
        __syncthreads();
    }
#pragma unroll
    for (int mt = 0; mt < 4; ++mt)
#pragma unroll
        for (int nt = 0; nt < 4; ++nt)
#pragma unroll
            for (int r = 0; r < 4; ++r) {
                int m = m0 + wm * 64 + mt * 16 + quad * 4 + r;
                int n = n0 + wn * 64 + nt * 16 + l16;
                u16 v = f2b(acc[mt][nt][r]);
                if (n < 2048) qraw[(size_t)m * 2048 + n] = v;
                else          kvraw[(size_t)m * 1024 + (n - 2048)] = v;
            }
}

// ---------------------------------------------------------------------------
// NT GEMM (out-projection): C[M][N] = A[M][K] * BT[N][K]^T, f32 out.
// R9-proven structure (single buffer).
// ---------------------------------------------------------------------------
__global__ __launch_bounds__(256) void gemm_nt(
    const u16* __restrict__ A, const u16* __restrict__ BT, float* __restrict__ C,
    int M, int N, int K) {
    __shared__ __align__(16) u16 As[128 * 64];
    __shared__ __align__(16) u16 Bs[128 * 64];
    const int tid  = threadIdx.x;
    const int lane = tid & 63;
    const int wave = tid >> 6;
    const int wm = wave >> 1, wn = wave & 1;
    const int quad = lane >> 4, l16 = lane & 15;
    const int lr = lane >> 3, lc = lane & 7;
    const int m0 = blockIdx.y * 128, n0 = blockIdx.x * 128;

    f32x4_t acc[4][4] = {};

    for (int k0 = 0; k0 < K; k0 += 64) {
#pragma unroll
        for (int i = 0; i < 4; ++i) {
            int rb = wave * 32 + i * 8;
            int r  = rb + lr;
            int sc = (lc ^ swz8(r)) << 3;
            gld16(A  + (size_t)(m0 + r) * K + k0 + sc, &As[rb * 64]);
            gld16(BT + (size_t)(n0 + r) * K + k0 + sc, &Bs[rb * 64]);
        }
        __syncthreads();
#pragma unroll
        for (int ks = 0; ks < 2; ++ks) {
            const int kch = ks * 4 + quad;
            bf16x8_t a[4], b[4];
#pragma unroll
            for (int mt = 0; mt < 4; ++mt) {
                int row = wm * 64 + mt * 16 + l16;
                a[mt] = *(const bf16x8_t*)(&As[row * 64 + ((kch ^ swz8(row)) << 3)]);
            }
#pragma unroll
            for (int nt = 0; nt < 4; ++nt) {
                int row = wn * 64 + nt * 16 + l16;
                b[nt] = *(const bf16x8_t*)(&Bs[row * 64 + ((kch ^ swz8(row)) << 3)]);
            }
#pragma unroll
            for (int mt = 0; mt < 4; ++mt)
#pragma unroll
                for (int nt = 0; nt < 4; ++nt)
                    acc[mt][nt] = __builtin_amdgcn_mfma_f32_16x16x32_bf16(
                        a[mt], b[nt], acc[mt][nt], 0, 0, 0);
        }
        __syncthreads();
    }
#pragma unroll
    for (int mt = 0; mt < 4; ++mt)
#pragma unroll
        for (int nt = 0; nt < 4; ++nt)
#pragma unroll
            for (int r = 0; r < 4; ++r) {
                int m = m0 + wm * 64 + mt * 16 + quad * 4 + r;
                int n = n0 + wn * 64 + nt * 16 + l16;
                C[(size_t)m * N + n] = acc[mt][nt][r];
            }
}

// ---------------------------------------------------------------------------
// Phase-3 fused kernel: rope_q + k_prep + v_prep + Wo transpose (R10 version,
// vectorized). grid = 8192 + 2048 + 2048 + 4096 = 16384 blocks.
// ---------------------------------------------------------------------------
__global__ __launch_bounds__(256) void prep3(
    u16* __restrict__ qraw, const u16* __restrict__ kvraw,
    float* __restrict__ kc, u16* __restrict__ kb,
    float* __restrict__ vc, u16* __restrict__ vt,
    const float* __restrict__ Wo, u16* __restrict__ WoT,
    const float* __restrict__ tab) {
    __shared__ u16 tls[32][33];
    const int id = blockIdx.x, tid = threadIdx.x;

    if (id < 8192) {                      // rope_q: 2 d's per thread
        int idx = id * 256 + tid;         // 2,097,152 total
        int d = (idx & 31) * 2;
        int t = idx >> 5;
        int h = t & 15; t >>= 4;
        int s = t & 2047;
        int b = t >> 11;
        size_t base = ((size_t)(b * S_ + s) * H_ + h) * DH_;
        unsigned int lo = *(const unsigned int*)(qraw + base + d);
        unsigned int hi = *(const unsigned int*)(qraw + base + d + 64);
        float4 cs = *(const float4*)(tab + ((size_t)((s << 6) | d)) * 2);
        float x1a = b2f((u16)lo), x1b = b2f((u16)(lo >> 16));
        float x2a = b2f((u16)hi), x2b = b2f((u16)(hi >> 16));
        float r1a = (x1a * cs.x - x2a * cs.y) * Q_SCALE;
        float r1b = (x1b * cs.z - x2b * cs.w) * Q_SCALE;
        float r2a = (x2a * cs.x + x1a * cs.y) * Q_SCALE;
        float r2b = (x2b * cs.z + x1b * cs.w) * Q_SCALE;
        *(unsigned int*)(qraw + base + d)      = (unsigned int)f2b(r1a) | ((unsigned int)f2b(r1b) << 16);
        *(unsigned int*)(qraw + base + d + 64) = (unsigned int)f2b(r2a) | ((unsigned int)f2b(r2b) << 16);
        return;
    }
    if (id < 10240) {                     // k_prep: 2 d's per thread
        int idx = (id - 8192) * 256 + tid;  // 524,288 total
        int d = (idx & 31) * 2;
        int t = idx >> 5;
        int g = t & 3; t >>= 2;
        int s = t & 2047;
        int b = t >> 11;
        const u16* src = kvraw + (size_t)(b * S_ + s) * 1024 + g * DH_;
        unsigned int lo = *(const unsigned int*)(src + d);
        unsigned int hi = *(const unsigned int*)(src + d + 64);
        float4 cs = *(const float4*)(tab + ((size_t)((s << 6) | d)) * 2);
        float x1a = b2f((u16)lo), x1b = b2f((u16)(lo >> 16));
        float x2a = b2f((u16)hi), x2b = b2f((u16)(hi >> 16));
        float r1a = x1a * cs.x - x2a * cs.y;
        float r1b = x1b * cs.z - x2b * cs.w;
        float r2a = x2a * cs.x + x1a * cs.y;
        float r2b = x2b * cs.z + x1b * cs.w;
        size_t o = ((size_t)(b * G_ + g) * S_ + s) * DH_;
        *(float2*)(kc + o + d)      = make_float2(r1a, r1b);
        *(float2*)(kc + o + d + 64) = make_float2(r2a, r2b);
        *(unsigned int*)(kb + o + d)      = (unsigned int)f2b(r1a) | ((unsigned int)f2b(r1b) << 16);
        *(unsigned int*)(kb + o + d + 64) = (unsigned int)f2b(r2a) | ((unsigned int)f2b(r2b) << 16);
        return;
    }
    if (id < 12288) {                     // v_prep
        int k = id - 10240;
        const int s0 = (k & 63) * 32, d0 = ((k >> 6) & 3) * 32;
        const int bg = k >> 8, b = bg >> 2, g = bg & 3;
        const int j = tid & 31, i = tid >> 5;
#pragma unroll
        for (int p = 0; p < 4; ++p) {
            int s = s0 + i + 8 * p;
            u16 v = kvraw[(size_t)(b * S_ + s) * 1024 + 512 + g * DH_ + d0 + j];
            tls[i + 8 * p][j] = v;
            vc[((size_t)bg * S_ + s) * DH_ + d0 + j] = b2f(v);
        }
        __syncthreads();
        const int j2 = tid & 15, i2 = tid >> 4;
#pragma unroll
        for (int p = 0; p < 2; ++p) {
            int col = i2 + 16 * p;        // d-local 0..31
            unsigned int w = (unsigned int)tls[2 * j2][col] |
                             ((unsigned int)tls[2 * j2 + 1][col] << 16);
            *(unsigned int*)(&vt[((size_t)bg * DH_ + d0 + col) * S_ + s0 + 2 * j2]) = w;
        }
        return;
    }
    {                                     // Wo transpose
        int k = id - 12288;
        const int c0 = (k & 63) * 32, r0 = (k >> 6) * 32;
        const int j = tid & 31, i = tid >> 5;
#pragma unroll
        for (int p = 0; p < 4; ++p)
            tls[i + 8 * p][j] = f2b(Wo[(size_t)(r0 + i + 8 * p) * 2048 + c0 + j]);
        __syncthreads();
        const int j2 = tid & 15, i2 = tid >> 4;
#pragma unroll
        for (int p = 0; p < 2; ++p) {
            int col = i2 + 16 * p;
            unsigned int w = (unsigned int)tls[2 * j2][col] |
                             ((unsigned int)tls[2 * j2 + 1][col] << 16);
            *(unsigned int*)(&WoT[(size_t)(c0 + col) * 2048 + r0 + 2 * j2]) = w;
        }
    }
}

// ---------------------------------------------------------------------------
// Flash attention v11: R10 structure + T5 s_setprio around MFMA clusters.
// 32x32 swapped QK^T, static-max softmax, split pairs, 32 KiB LDS, gld16
// staging, 2 blocks/CU. setprio(1) biases the CU scheduler toward the wave
// in its MFMA cluster while the co-resident block's waves issue memory ops
// (m191: +4-7% attn; correctness-neutral hint).
// ---------------------------------------------------------------------------
__global__ __launch_bounds__(256, 2) void flash_attn(
    const u16* __restrict__ q, const u16* __restrict__ kb,
    const u16* __restrict__ vt, u16* __restrict__ ctx) {
    __shared__ __align__(16) u16 Ks[64 * 128];   // [kv 64][d 128], swizzled
    __shared__ __align__(16) u16 Vs[128 * 64];   // [d 128][kv 64], swizzled

    const int tid  = threadIdx.x;
    const int lane = tid & 63;
    const int wave = tid >> 6;
    const int hi = lane >> 5, l31 = lane & 31;

    const int id = blockIdx.x;
    const int tslot = id & 7;
    const int h = (id >> 3) & 15;
    const int b = (id >> 7) & 1;
    const int tile = (id >> 8) ? (15 - tslot) : tslot;
    const int g = h >> 2;  // H/G = 4

    const u16* Kp  = kb + (size_t)(b * G_ + g) * S_ * DH_;
    const u16* Vtp = vt + (size_t)(b * G_ + g) * DH_ * S_;

    int krow[4], ksc[4], vrow[4], vsc[4];
#pragma unroll
    for (int i = 0; i < 4; ++i) {
        int c = tid + 256 * i;
        krow[i] = c >> 4; ksc[i] = (((c & 15) ^ swz8(c >> 4)) << 3);
        vrow[i] = c >> 3; vsc[i] = (((c & 7) ^ swz8(c >> 3)) << 3);
    }

    const int t0 = tile * 128;
    const int q0w = t0 + wave * 32;
    const int niter = 2 * tile + 2;

    auto stageK = [&](int t) {
        const u16* src = Kp + (size_t)t * 64 * DH_;
#pragma unroll
        for (int i = 0; i < 4; ++i)
            gld16(src + (size_t)krow[i] * DH_ + ksc[i], &Ks[wave * 512 + i * 2048]);
    };
    auto stageV = [&](int t) {
        const u16* src = Vtp + t * 64;
#pragma unroll
        for (int i = 0; i < 4; ++i)
            gld16(src + (size_t)vrow[i] * S_ + vsc[i], &Vs[wave * 512 + i * 2048]);
    };

    bf16x8_t qf[8];
#pragma unroll
    for (int dk = 0; dk < 8; ++dk)
        qf[dk] = *(const bf16x8_t*)(
            q + ((size_t)(b * S_ + q0w + l31) * H_ + h) * DH_ + dk * 16 + hi * 8);

    f32x16_t o[4] = {};   // O[q=crow(r,hi)][d = nb*32 + l31]
    float l_i = 0.f;

    stageK(0);
    stageV(0);
    __syncthreads();

    for (int it = 0; it < niter; ++it) {
        const int kv0 = it * 64;
        const bool comp = (q0w + 31 >= kv0);  // wave-uniform

        f32x16_t s[2] = {};
        if (comp) {
            __builtin_amdgcn_s_setprio(1);
#pragma unroll
            for (int dk = 0; dk < 8; ++dk) {
                const int col = dk * 16 + hi * 8;
                bf16x8_t kf0 = *(const bf16x8_t*)(
                    &Ks[l31 * 128 + (col ^ kxor(l31))]);
                bf16x8_t kf1 = *(const bf16x8_t*)(
                    &Ks[(32 + l31) * 128 + (col ^ kxor(32 + l31))]);
                s[0] = __builtin_amdgcn_mfma_f32_32x32x16_bf16(kf0, qf[dk], s[0], 0, 0, 0);
                s[1] = __builtin_amdgcn_mfma_f32_32x32x16_bf16(kf1, qf[dk], s[1], 0, 0, 0);
            }
            __builtin_amdgcn_s_setprio(0);
        }
        __syncthreads();                 // V(it) visible; all waves done with Ks
        if (it + 1 < niter) stageK(it + 1);

        if (comp) {
            if (kv0 + 63 > q0w) {
                const int qg = q0w + l31;
#pragma unroll
                for (int t = 0; t < 2; ++t)
#pragma unroll
                    for (int r = 0; r < 16; ++r) {
                        int kvr = kv0 + t * 32 + (r & 3) + 8 * (r >> 2) + 4 * hi;
                        if (kvr > qg) s[t][r] = NEG_SENTINEL;
                    }
            }
            // static-max softmax: P = exp2(s) directly
            float sum[16];
#pragma unroll
            for (int i = 0; i < 16; ++i) {
                float p0 = exp2f(s[0][i]);
                float p1 = exp2f(s[1][i]);
                s[0][i] = p0; s[1][i] = p1;
                sum[i] = p0 + p1;
            }
#pragma unroll
            for (int w = 8; w >= 1; w >>= 1)
#pragma unroll
                for (int i = 0; i < w; ++i) sum[i] += sum[i + w];
            l_i += sum[0] + __shfl_xor(sum[0], 32);

            bf16x8_t pa[4];
#pragma unroll
            for (int ks = 0; ks < 4; ++ks) {
                const int t = ks >> 1, u8 = (ks & 1) * 8;
                unsigned int a0 = cvtpk_bf16(s[t][u8 + 0], s[t][u8 + 1]);
                unsigned int a1 = cvtpk_bf16(s[t][u8 + 2], s[t][u8 + 3]);
                unsigned int b0 = cvtpk_bf16(s[t][u8 + 4], s[t][u8 + 5]);
                unsigned int b1 = cvtpk_bf16(s[t][u8 + 6], s[t][u8 + 7]);
                asm("v_permlane32_swap_b32 %0, %1" : "+v"(a0), "+v"(b0));
                asm("v_permlane32_swap_b32 %0, %1" : "+v"(a1), "+v"(b1));
                union { unsigned int w[4]; bf16x8_t v; } pk;
                pk.w[0] = a0; pk.w[1] = a1; pk.w[2] = b0; pk.w[3] = b1;
                pa[ks] = pk.v;
            }
            __builtin_amdgcn_s_setprio(1);
#pragma unroll
            for (int ks = 0; ks < 4; ++ks) {
                const int col = ks * 16 + hi * 8;
#pragma unroll
                for (int nb = 0; nb < 4; ++nb) {
                    const int row = nb * 32 + l31;
                    bf16x8_t vb = *(const bf16x8_t*)(
                        &Vs[row * 64 + (col ^ kxor(row))]);
                    o[nb] = __builtin_amdgcn_mfma_f32_32x32x16_bf16(
                        pa[ks], vb, o[nb], 0, 0, 0);
                }
            }
            __builtin_amdgcn_s_setprio(0);
        }
        __syncthreads();                 // K(it+1) visible; all waves done with Vs
        if (it + 1 < niter) stageV(it + 1);
    }
    float il = 1.f / l_i;
#pragma unroll
    for (int r = 0; r < 16; ++r) {
        const int crow = (r & 3) + 8 * (r >> 2) + 4 * hi;
        float ilr = __shfl(il, crow);
        const int s_idx = q0w + crow;
#pragma unroll
        for (int nb = 0; nb < 4; ++nb)
            ctx[((size_t)(b * S_ + s_idx) * H_ + h) * DH_ + nb * 32 + l31] =
                f2b(o[nb][r] * ilr);
    }
}

// ---------------------------------------------------------------------------
extern "C" void kernel_launch(void* const* d_in, const int* in_sizes, int n_in,
                              void* d_out, int out_size, void* d_ws, size_t ws_size,
                              hipStream_t stream) {
    const float* x  = (const float*)d_in[0];
    const float* Wq = (const float*)d_in[1];
    const float* Wk = (const float*)d_in[2];
    const float* Wv = (const float*)d_in[3];
    const float* Wo = (const float*)d_in[4];
    // d_in[5] = mask (unused; causal computed analytically)

    float* out    = (float*)d_out;                           // [B][S][H*DH]  8,388,608 f32
    float* kc_out = out + (size_t)B_ * S_ * H_ * DH_;        // [B][G][S][DH] 2,097,152 f32
    float* vc_out = kc_out + (size_t)B_ * G_ * S_ * DH_;     // [B][G][S][DH] 2,097,152 f32

    // Borrow `out` f32 region (= 16M u16) as early scratch; both buffers are
    // dead before the final gemm writes `out` (single stream, serialized).
    u16* outw = (u16*)d_out;
    u16* xb   = outw;             // 8M u16, live phases 1-2 (x cast to bf16)
    u16* qraw = outw + 8388608;   // 8M u16, live phases 2-4

    // Workspace overlays (u16 offsets; phases single-stream serialized):
    u16* ws    = (u16*)d_ws;
    u16* WqT   = ws;              // 4M u16, phases 1-2  [bytes 0..8M)
    u16* WoT   = ws;              // 4M u16, phases 3-5  (same slot, after proj)
    u16* WkvT  = ws + 4194304;    // 2M u16, phases 1-2  [8M..12M) -- contiguous
                                  //   with WqT => fused BT[3072][2048]
    u16* kb    = ws + 4194304;    // 2M u16, phases 3-4
    u16* vt    = ws + 6291456;    // 2M u16, phases 3-4  [12M..16.8M)
    u16* kvraw = ws + 8388608;    // 4M u16, phases 2-3  [16.8M..25.2M)
    u16* ctx   = ws + 8388608;    // 8M u16, phases 4-5
    float* tab = (float*)(ws + 12582912);  // 1 MB trig table, phases 1-3
                                           // (inside ctx region, dead by ph 4)

    dim3 blk(256);
    // phase 1: trig + cast + Wq/Wk/Wv transposes (one launch)
    prep1<<<dim3(10752), blk, 0, stream>>>(x, Wq, Wk, Wv, xb, WqT, WkvT, tab);

    // phase 2: fused q+kv projection (768 blocks = 3/CU)
    gemm_proj<<<dim3(24, 32), blk, 0, stream>>>(xb, WqT, qraw, kvraw);

    // phase 3: rope_q + k_prep + v_prep + Wo transpose (one launch, vectorized)
    prep3<<<dim3(16384), blk, 0, stream>>>(qraw, kvraw, kc_out, kb, vc_out, vt,
                                           Wo, WoT, tab);

    // phase 4: attention (static-max softmax, split pairs, 2 blocks/CU, T5)
    flash_attn<<<dim3(512), blk, 0, stream>>>(qraw, kb, vt, ctx);

    // phase 5: output projection (f32 out)
    gemm_nt<<<dim3(16, 32), blk, 0, stream>>>(ctx, WoT, out, 4096, 2048, 2048);
}